// Round 4
// baseline (300.000 us; speedup 1.0000x reference)
//
#include <hip/hip_runtime.h>
#include <hip/hip_bf16.h>
#include <cmath>

typedef __bf16 bf16_t;
typedef __bf16 bf16x8 __attribute__((ext_vector_type(8)));
typedef __bf16 bf16x4 __attribute__((ext_vector_type(4)));
typedef float f32x4 __attribute__((ext_vector_type(4)));

#define AS1 __attribute__((address_space(1)))
#define AS3 __attribute__((address_space(3)))

__device__ __forceinline__ void async_lds16(const void* g, void* s) {
    __builtin_amdgcn_global_load_lds((const AS1 void*)g, (AS3 void*)s, 16, 0, 0);
}

// ---------------- weight transpose + cast: src (R x C) f32 -> dst (C x R) bf16
__global__ __launch_bounds__(256) void k_transpose_bf16(
    const float* __restrict__ src, bf16_t* __restrict__ dst, int R, int C) {
    __shared__ float tile[32][33];
    const int tx = threadIdx.x & 31, ty = threadIdx.x >> 5;
    const int r0 = blockIdx.y << 5, c0 = blockIdx.x << 5;
#pragma unroll
    for (int i = 0; i < 32; i += 8)
        tile[ty + i][tx] = src[(size_t)(r0 + ty + i) * C + c0 + tx];
    __syncthreads();
#pragma unroll
    for (int i = 0; i < 32; i += 8)
        dst[(size_t)(c0 + ty + i) * R + r0 + tx] = (bf16_t)tile[tx][ty + i];
}

// ---------------- layernorm: x (rows x 1024) f32 -> out bf16
__global__ __launch_bounds__(256) void k_layernorm(
    const float* __restrict__ x, const float* __restrict__ g,
    const float* __restrict__ b, bf16_t* __restrict__ out) {
    const int row = blockIdx.x;
    const int t = threadIdx.x;
    const float4 xv = reinterpret_cast<const float4*>(x + (size_t)row * 1024)[t];
    float s = xv.x + xv.y + xv.z + xv.w;
    float s2 = xv.x * xv.x + xv.y * xv.y + xv.z * xv.z + xv.w * xv.w;
#pragma unroll
    for (int mk = 32; mk >= 1; mk >>= 1) {
        s += __shfl_xor(s, mk);
        s2 += __shfl_xor(s2, mk);
    }
    __shared__ float red[8];
    const int w = t >> 6, l = t & 63;
    if (l == 0) { red[w] = s; red[4 + w] = s2; }
    __syncthreads();
    s = red[0] + red[1] + red[2] + red[3];
    s2 = red[4] + red[5] + red[6] + red[7];
    const float mu = s * (1.0f / 1024.0f);
    const float var = s2 * (1.0f / 1024.0f) - mu * mu;
    const float rs = rsqrtf(var + 1e-5f);
    const float4 gv = reinterpret_cast<const float4*>(g)[t];
    const float4 bv = reinterpret_cast<const float4*>(b)[t];
    bf16x4 o4;
    o4[0] = (bf16_t)((xv.x - mu) * rs * gv.x + bv.x);
    o4[1] = (bf16_t)((xv.y - mu) * rs * gv.y + bv.y);
    o4[2] = (bf16_t)((xv.z - mu) * rs * gv.z + bv.z);
    o4[3] = (bf16_t)((xv.w - mu) * rs * gv.w + bv.w);
    *reinterpret_cast<bf16x4*>(out + (size_t)row * 1024 + t * 4) = o4;
}

// ---------------- 256-wide-tile 8-wave phase-pipelined GEMM
// C = A(MxK,bf16) * BT(NxK,bf16)^T + epilogue. BM=256, BK=64, BN in {256,128}.
// 8 waves (2M x 4N), per-wave output 128 x BN/4. Double-buffered LDS
// (A 64KB + B 32/64KB). Raw s_barrier + counted vmcnt (never 0 mid-loop).
// LDS rows = 64 bf16 (8 x 16B chunks), swizzle chunk^=(row&7) on both the
// pre-swizzled global staging source and the ds_read address (rule #21).
enum { EPI_QKV = 0, EPI_RESID = 1, EPI_GELU = 2 };

template <int EPI, int BN>
__global__ __launch_bounds__(512, 2) void k_gemm8(
    const bf16_t* __restrict__ A, const bf16_t* __restrict__ BT,
    const float* __restrict__ bias0, const float* __restrict__ bias1,
    const float* __restrict__ bias2, const float* __restrict__ resid,
    float* __restrict__ outF, bf16_t* __restrict__ outB,
    bf16_t* __restrict__ outB2, bf16_t* __restrict__ outB3,
    int M, int N, int K) {
    constexpr int BM = 256;
    constexpr int FJ = BN / 64;       // frag-cols per wave
    constexpr int FJH = FJ / 2;       // frag-cols per col-half
    constexpr int AISS = BM / 64;     // stage issues for A (4)
    constexpr int BISS = BN / 64;     // stage issues for B (4 or 2)
    constexpr int LT = AISS + BISS;   // loads/tile/thread

    const int gx = gridDim.x;
    const int nwg = gx * gridDim.y;
    int lin = blockIdx.y * gx + blockIdx.x;
    if ((nwg & 7) == 0) lin = (lin & 7) * (nwg >> 3) + (lin >> 3);
    const int mbase = (lin / gx) * BM;
    const int nbase = (lin % gx) * BN;

    const int t = threadIdx.x;
    const int w = t >> 6, l = t & 63;
    const int wr = w >> 2, wc = w & 3;
    const int lrow = l & 15, lg = l >> 4;

    __shared__ alignas(16) bf16_t As[2][BM * 64];
    __shared__ alignas(16) bf16_t Bs[2][BN * 64];

    f32x4 acc[8][FJ] = {};

    const int sr8 = t >> 3;                    // staging row 0..63
    const int ssw8 = ((t & 7) ^ (sr8 & 7)) * 8;  // pre-swizzled src chunk

    auto stage = [&](int kt, int buf) {
        const int k0 = kt << 6;
#pragma unroll
        for (int i = 0; i < AISS; i++)
            async_lds16(A + (size_t)(mbase + i * 64 + sr8) * K + k0 + ssw8,
                        &As[buf][i * 4096 + t * 8]);
#pragma unroll
        for (int i = 0; i < BISS; i++)
            async_lds16(BT + (size_t)(nbase + i * 64 + sr8) * K + k0 + ssw8,
                        &Bs[buf][i * 4096 + t * 8]);
    };

#define LOAD_A(H)                                                          \
    _Pragma("unroll") for (int fi = 0; fi < 4; fi++) {                     \
        const int r_ = wr * 128 + (H) * 64 + fi * 16 + lrow;               \
        _Pragma("unroll") for (int ks = 0; ks < 2; ks++) {                 \
            const int c_ = ks * 4 + lg;                                    \
            afr[fi][ks] = *reinterpret_cast<const bf16x8*>(                \
                &As[cur][r_ * 64 + ((c_ ^ (r_ & 7)) * 8)]);                \
        }                                                                  \
    }
#define LOAD_B(V, DST)                                                     \
    _Pragma("unroll") for (int fj = 0; fj < FJH; fj++) {                   \
        const int rb_ = wc * (BN / 4) + (V) * (BN / 8) + fj * 16 + lrow;   \
        _Pragma("unroll") for (int ks = 0; ks < 2; ks++) {                 \
            const int c_ = ks * 4 + lg;                                    \
            DST[fj][ks] = *reinterpret_cast<const bf16x8*>(                \
                &Bs[cur][rb_ * 64 + ((c_ ^ (rb_ & 7)) * 8)]);              \
        }                                                                  \
    }
#define MFMA_Q(H, V, BF)                                                   \
    __builtin_amdgcn_s_setprio(1);                                         \
    _Pragma("unroll") for (int fi = 0; fi < 4; fi++)                       \
    _Pragma("unroll") for (int fj = 0; fj < FJH; fj++)                     \
    _Pragma("unroll") for (int ks = 0; ks < 2; ks++)                       \
        acc[(H) * 4 + fi][(V) * FJH + fj] =                                \
            __builtin_amdgcn_mfma_f32_16x16x32_bf16(                       \
                afr[fi][ks], BF[fj][ks],                                   \
                acc[(H) * 4 + fi][(V) * FJH + fj], 0, 0, 0);               \
    __builtin_amdgcn_s_setprio(0);

    stage(0, 0);
    stage(1, 1);
    asm volatile("s_waitcnt vmcnt(%0)" ::"i"(LT) : "memory");
    __builtin_amdgcn_sched_barrier(0);
    __builtin_amdgcn_s_barrier();

    const int nt = K >> 6;
    bf16x8 afr[4][2], b0[FJH][2], b1[FJH][2];
    for (int kt = 0; kt < nt; kt++) {
        const int cur = kt & 1;
        // phase 0: quadrant (h0, v0)
        LOAD_A(0)
        LOAD_B(0, b0)
        asm volatile("s_waitcnt lgkmcnt(0)" ::: "memory");
        __builtin_amdgcn_sched_barrier(0);
        MFMA_Q(0, 0, b0)
        // phase 1: quadrant (h0, v1)
        LOAD_B(1, b1)
        asm volatile("s_waitcnt lgkmcnt(0)" ::: "memory");
        __builtin_amdgcn_sched_barrier(0);
        MFMA_Q(0, 1, b1)
        // phase 2: read A-half1, retire all reads of buf[cur], then barrier
        LOAD_A(1)
        asm volatile("s_waitcnt lgkmcnt(0)" ::: "memory");
        __builtin_amdgcn_sched_barrier(0);
        __builtin_amdgcn_s_barrier();
        // stage tile kt+2 into the just-freed buffer; overlap with q2,q3
        const bool do_stage = (kt + 2) < nt;
        if (do_stage) stage(kt + 2, cur);
        MFMA_Q(1, 1, b1)
        MFMA_Q(1, 0, b0)
        // tile kt+1 (issued last iter) must be landed before next iter reads
        if (do_stage) {
            asm volatile("s_waitcnt vmcnt(%0)" ::"i"(LT) : "memory");
        } else {
            asm volatile("s_waitcnt vmcnt(0)" ::: "memory");
        }
        __builtin_amdgcn_sched_barrier(0);
        __builtin_amdgcn_s_barrier();
    }

#pragma unroll
    for (int i = 0; i < 8; i++) {
#pragma unroll
        for (int j = 0; j < FJ; j++) {
            const int col = nbase + wc * (BN / 4) + j * 16 + lrow;
            float bj;
            int kind = 0, cc = col;
            if constexpr (EPI == EPI_QKV) {
                kind = col >> 10; cc = col & 1023;
                bj = (kind == 0 ? bias0 : kind == 1 ? bias1 : bias2)[cc];
            } else {
                bj = bias0[col];
            }
#pragma unroll
            for (int r = 0; r < 4; r++) {
                const int row = mbase + wr * 128 + i * 16 + lg * 4 + r;
                float v = acc[i][j][r] + bj;
                if constexpr (EPI == EPI_QKV) {
                    const int bidx = row >> 10, ns = row & 1023;
                    const int hh = cc >> 6, ch = cc & 63;
                    const int bhh = bidx * 16 + hh;
                    if (kind == 0)
                        outB[((size_t)bhh * 1024 + ns) * 64 + ch] = (bf16_t)(v * 0.125f);
                    else if (kind == 1)
                        outB2[((size_t)bhh * 1024 + ns) * 64 + ch] = (bf16_t)v;
                    else  // V stored transposed: [bh][ch][n]
                        outB3[((size_t)bhh * 64 + ch) * 1024 + ns] = (bf16_t)v;
                } else if constexpr (EPI == EPI_RESID) {
                    outF[(size_t)row * N + col] = v + resid[(size_t)row * N + col];
                } else {  // EPI_GELU, exact
                    const float ge = 0.5f * v * (1.0f + erff(v * 0.70710678118654752f));
                    outB[(size_t)row * N + col] = (bf16_t)ge;
                }
            }
        }
    }
#undef LOAD_A
#undef LOAD_B
#undef MFMA_Q
}

// ---------------- flash attention, causal, 1 block per (bh, 64-row q tile)
__global__ __launch_bounds__(256, 2) void k_attn(
    const bf16_t* __restrict__ q, const bf16_t* __restrict__ kk,
    const bf16_t* __restrict__ vt, const unsigned char* __restrict__ pad,
    bf16_t* __restrict__ o) {
    const int qt = blockIdx.x;   // 0..15
    const int bh = blockIdx.y;   // 0..63
    const int bb = bh >> 4, hh = bh & 15;
    const int t = threadIdx.x;
    const int w = t >> 6, l = t & 63;
    const int lrow = l & 15, lg = l >> 4;
    const int qbase = qt * 64;

    __shared__ alignas(16) bf16_t Ks[64 * 64];
    __shared__ alignas(16) bf16_t Vs[64 * 64];
    __shared__ alignas(16) bf16_t Ps[4][16 * 64];

    const size_t bh_off = (size_t)bh * 1024 * 64;
    const int qrow = qbase + w * 16 + lrow;
    bf16x8 qf[2];
#pragma unroll
    for (int ks = 0; ks < 2; ks++)
        qf[ks] = *reinterpret_cast<const bf16x8*>(q + bh_off + (size_t)qrow * 64 + ks * 32 + lg * 8);

    f32x4 oacc[4] = {};
    float mrow[4] = {-1e30f, -1e30f, -1e30f, -1e30f};
    float lsum[4] = {0.f, 0.f, 0.f, 0.f};

    const int sr = t >> 3;                // staging row 0..31
    const int ssw = ((t & 7) ^ (sr & 7)) * 8;  // swizzled source chunk offset

    for (int kb = 0; kb < qbase + 64; kb += 64) {
        __syncthreads();
        const bf16_t* kp = kk + bh_off + (size_t)kb * 64;
        async_lds16(kp + (size_t)sr * 64 + ssw, Ks + t * 8);
        async_lds16(kp + (size_t)(32 + sr) * 64 + ssw, Ks + 2048 + t * 8);
        const bf16_t* vp = vt + bh_off + kb;  // rows = channel, stride 1024
        async_lds16(vp + (size_t)sr * 1024 + ssw, Vs + t * 8);
        async_lds16(vp + (size_t)(32 + sr) * 1024 + ssw, Vs + 2048 + t * 8);
        __syncthreads();

        // S = Q K^T (16 q rows x 64 kv per wave)
        f32x4 s[4] = {};
#pragma unroll
        for (int ks = 0; ks < 2; ks++) {
#pragma unroll
            for (int jt = 0; jt < 4; jt++) {
                const int kr = jt * 16 + lrow;
                bf16x8 bfr = *reinterpret_cast<const bf16x8*>(
                    Ks + kr * 64 + (((ks * 4 + lg) ^ (kr & 7)) * 8));
                s[jt] = __builtin_amdgcn_mfma_f32_16x16x32_bf16(qf[ks], bfr, s[jt], 0, 0, 0);
            }
        }
        // causal + pad mask
#pragma unroll
        for (int jt = 0; jt < 4; jt++) {
            const int kvg = kb + jt * 16 + lrow;
            const bool padm = pad[bb * 1024 + kvg] != 0;
#pragma unroll
            for (int r = 0; r < 4; r++) {
                const int qg = qbase + w * 16 + lg * 4 + r;
                if (kvg > qg || padm) s[jt][r] = -1e30f;
            }
        }
        // online softmax (row groups of 16 lanes)
        float alpha[4];
#pragma unroll
        for (int r = 0; r < 4; r++) {
            float mx = fmaxf(fmaxf(s[0][r], s[1][r]), fmaxf(s[2][r], s[3][r]));
#pragma unroll
            for (int mk = 8; mk >= 1; mk >>= 1) mx = fmaxf(mx, __shfl_xor(mx, mk));
            const float mn = fmaxf(mrow[r], mx);
            alpha[r] = __expf(mrow[r] - mn);
            mrow[r] = mn;
        }
#pragma unroll
        for (int jt = 0; jt < 4; jt++)
#pragma unroll
            for (int r = 0; r < 4; r++)
                s[jt][r] = __expf(s[jt][r] - mrow[r]);
#pragma unroll
        for (int r = 0; r < 4; r++) {
            float sm = s[0][r] + s[1][r] + s[2][r] + s[3][r];
#pragma unroll
            for (int mk = 8; mk >= 1; mk >>= 1) sm += __shfl_xor(sm, mk);
            lsum[r] = lsum[r] * alpha[r] + sm;
        }
#pragma unroll
        for (int ct = 0; ct < 4; ct++)
#pragma unroll
            for (int r = 0; r < 4; r++)
                oacc[ct][r] *= alpha[r];
        // P -> LDS (per wave), swizzled, convert to A-fragment layout
#pragma unroll
        for (int jt = 0; jt < 4; jt++)
#pragma unroll
            for (int r = 0; r < 4; r++) {
                const int prow = lg * 4 + r;
                const int kvc = jt * 16 + lrow;
                Ps[w][prow * 64 + (((kvc >> 3) ^ (prow & 7)) * 8) + (kvc & 7)] = (bf16_t)s[jt][r];
            }
        // PV (same-wave LDS RAW; compiler orders DS ops within a wave)
#pragma unroll
        for (int ks = 0; ks < 2; ks++) {
            bf16x8 pa = *reinterpret_cast<const bf16x8*>(
                &Ps[w][lrow * 64 + (((ks * 4 + lg) ^ (lrow & 7)) * 8)]);
#pragma unroll
            for (int ct = 0; ct < 4; ct++) {
                const int vr = ct * 16 + lrow;
                bf16x8 vb = *reinterpret_cast<const bf16x8*>(
                    Vs + vr * 64 + (((ks * 4 + lg) ^ (vr & 7)) * 8));
                oacc[ct] = __builtin_amdgcn_mfma_f32_16x16x32_bf16(pa, vb, oacc[ct], 0, 0, 0);
            }
        }
    }
    // epilogue: o[b][n][h*64+ch] bf16
#pragma unroll
    for (int ct = 0; ct < 4; ct++) {
#pragma unroll
        for (int r = 0; r < 4; r++) {
            const int qg = qbase + w * 16 + lg * 4 + r;
            const float val = oacc[ct][r] / lsum[r];
            o[((size_t)bb * 1024 + qg) * 1024 + hh * 64 + ct * 16 + lrow] = (bf16_t)val;
        }
    }
}

extern "C" void kernel_launch(void* const* d_in, const int* in_sizes, int n_in,
                              void* d_out, int out_size, void* d_ws, size_t ws_size,
                              hipStream_t stream) {
    const float* x    = (const float*)d_in[0];
    const float* ln1g = (const float*)d_in[1];
    const float* ln1b = (const float*)d_in[2];
    const float* Wq   = (const float*)d_in[3];
    const float* bq   = (const float*)d_in[4];
    const float* Wk   = (const float*)d_in[5];
    const float* bk   = (const float*)d_in[6];
    const float* Wv   = (const float*)d_in[7];
    const float* bv   = (const float*)d_in[8];
    const float* Wo   = (const float*)d_in[9];
    const float* bo   = (const float*)d_in[10];
    const float* ln2g = (const float*)d_in[11];
    const float* ln2b = (const float*)d_in[12];
    const float* W1   = (const float*)d_in[13];
    const float* b1   = (const float*)d_in[14];
    const float* W2   = (const float*)d_in[15];
    const float* b2   = (const float*)d_in[16];
    const unsigned char* pad = (const unsigned char*)d_in[17];

    char* ws = (char*)d_ws;
    const size_t MB = 1024 * 1024;
    bf16_t* WqkvT = (bf16_t*)(ws + 0 * MB);   // 3072x1024 bf16 = 6MB
    bf16_t* WoT = (bf16_t*)(ws + 6 * MB);     // 2MB
    bf16_t* W1T = (bf16_t*)(ws + 8 * MB);     // 8MB
    bf16_t* W2T = (bf16_t*)(ws + 16 * MB);    // 8MB
    bf16_t* h   = (bf16_t*)(ws + 24 * MB);    // 8MB
    bf16_t* qb  = (bf16_t*)(ws + 32 * MB);    // 8MB
    bf16_t* kb  = (bf16_t*)(ws + 40 * MB);    // 8MB
    bf16_t* vb  = (bf16_t*)(ws + 48 * MB);    // 8MB (transposed [bh][ch][n])
    bf16_t* hid = (bf16_t*)(ws + 24 * MB);    // 32MB, overlays h,q,k,v (dead by then)
    bf16_t* ob  = (bf16_t*)(ws + 56 * MB);    // 8MB
    bf16_t* m2  = (bf16_t*)(ws + 56 * MB);    // overlays ob (dead by then)
    float*  x2  = (float*)(ws + 64 * MB);     // 16MB; total 80MB

    const dim3 blk(256);
    const dim3 blk8(512);
    // weight transposes (f32 -> bf16, W^T); q/k/v packed into one 3072-row BT
    k_transpose_bf16<<<dim3(32, 32), blk, 0, stream>>>(Wq, WqkvT, 1024, 1024);
    k_transpose_bf16<<<dim3(32, 32), blk, 0, stream>>>(Wk, WqkvT + 1024 * 1024, 1024, 1024);
    k_transpose_bf16<<<dim3(32, 32), blk, 0, stream>>>(Wv, WqkvT + 2048 * 1024, 1024, 1024);
    k_transpose_bf16<<<dim3(32, 32), blk, 0, stream>>>(Wo, WoT, 1024, 1024);
    k_transpose_bf16<<<dim3(128, 32), blk, 0, stream>>>(W1, W1T, 1024, 4096);
    k_transpose_bf16<<<dim3(32, 128), blk, 0, stream>>>(W2, W2T, 4096, 1024);
    // LN1
    k_layernorm<<<4096, blk, 0, stream>>>(x, ln1g, ln1b, h);
    // fused QKV projection: M=4096, N=3072, K=1024 -> 12x16 = 192 blocks
    k_gemm8<EPI_QKV, 256><<<dim3(12, 16), blk8, 0, stream>>>(
        h, WqkvT, bq, bk, bv, nullptr, nullptr, qb, kb, vb, 4096, 3072, 1024);
    // attention
    k_attn<<<dim3(16, 64), blk, 0, stream>>>(qb, kb, vb, pad, ob);
    // O projection + residual -> x2 (f32): N=1024 -> BN=128, 8x16 = 128 blocks
    k_gemm8<EPI_RESID, 128><<<dim3(8, 16), blk8, 0, stream>>>(
        ob, WoT, bo, nullptr, nullptr, x, x2, nullptr, nullptr, nullptr, 4096, 1024, 1024);
    // LN2
    k_layernorm<<<4096, blk, 0, stream>>>(x2, ln2g, ln2b, m2);
    // MLP up + GELU: M=4096, N=4096, K=1024 -> 16x16 = 256 blocks
    k_gemm8<EPI_GELU, 256><<<dim3(16, 16), blk8, 0, stream>>>(
        m2, W1T, b1, nullptr, nullptr, nullptr, nullptr, hid, nullptr, nullptr, 4096, 4096, 1024);
    // MLP down + residual: M=4096, N=1024, K=4096 -> 8x16 = 128 blocks
    k_gemm8<EPI_RESID, 128><<<dim3(8, 16), blk8, 0, stream>>>(
        hid, W2T, b2, nullptr, nullptr, x2, (float*)d_out, nullptr, nullptr, nullptr, 4096, 1024, 4096);
}

// Round 6
// 286.767 us; speedup vs baseline: 1.0461x; 1.0461x over previous
//
#include <hip/hip_runtime.h>
#include <hip/hip_bf16.h>
#include <cmath>

typedef __bf16 bf16_t;
typedef __bf16 bf16x8 __attribute__((ext_vector_type(8)));
typedef __bf16 bf16x4 __attribute__((ext_vector_type(4)));
typedef float f32x4 __attribute__((ext_vector_type(4)));

#define AS1 __attribute__((address_space(1)))
#define AS3 __attribute__((address_space(3)))

__device__ __forceinline__ void async_lds16(const void* g, void* s) {
    __builtin_amdgcn_global_load_lds((const AS1 void*)g, (AS3 void*)s, 16, 0, 0);
}

// ---------------- weight transpose + cast: src (R x C) f32 -> dst (C x R) bf16
__global__ __launch_bounds__(256) void k_transpose_bf16(
    const float* __restrict__ src, bf16_t* __restrict__ dst, int R, int C) {
    __shared__ float tile[32][33];
    const int tx = threadIdx.x & 31, ty = threadIdx.x >> 5;
    const int r0 = blockIdx.y << 5, c0 = blockIdx.x << 5;
#pragma unroll
    for (int i = 0; i < 32; i += 8)
        tile[ty + i][tx] = src[(size_t)(r0 + ty + i) * C + c0 + tx];
    __syncthreads();
#pragma unroll
    for (int i = 0; i < 32; i += 8)
        dst[(size_t)(c0 + ty + i) * R + r0 + tx] = (bf16_t)tile[tx][ty + i];
}

// ---------------- layernorm: x (rows x 1024) f32 -> out bf16
__global__ __launch_bounds__(256) void k_layernorm(
    const float* __restrict__ x, const float* __restrict__ g,
    const float* __restrict__ b, bf16_t* __restrict__ out) {
    const int row = blockIdx.x;
    const int t = threadIdx.x;
    const float4 xv = reinterpret_cast<const float4*>(x + (size_t)row * 1024)[t];
    float s = xv.x + xv.y + xv.z + xv.w;
    float s2 = xv.x * xv.x + xv.y * xv.y + xv.z * xv.z + xv.w * xv.w;
#pragma unroll
    for (int mk = 32; mk >= 1; mk >>= 1) {
        s += __shfl_xor(s, mk);
        s2 += __shfl_xor(s2, mk);
    }
    __shared__ float red[8];
    const int w = t >> 6, l = t & 63;
    if (l == 0) { red[w] = s; red[4 + w] = s2; }
    __syncthreads();
    s = red[0] + red[1] + red[2] + red[3];
    s2 = red[4] + red[5] + red[6] + red[7];
    const float mu = s * (1.0f / 1024.0f);
    const float var = s2 * (1.0f / 1024.0f) - mu * mu;
    const float rs = rsqrtf(var + 1e-5f);
    const float4 gv = reinterpret_cast<const float4*>(g)[t];
    const float4 bv = reinterpret_cast<const float4*>(b)[t];
    bf16x4 o4;
    o4[0] = (bf16_t)((xv.x - mu) * rs * gv.x + bv.x);
    o4[1] = (bf16_t)((xv.y - mu) * rs * gv.y + bv.y);
    o4[2] = (bf16_t)((xv.z - mu) * rs * gv.z + bv.z);
    o4[3] = (bf16_t)((xv.w - mu) * rs * gv.w + bv.w);
    *reinterpret_cast<bf16x4*>(out + (size_t)row * 1024 + t * 4) = o4;
}

// ---------------- partial reduce + bias + residual + fused LN -> x2 (f32), m2 (bf16)
__global__ __launch_bounds__(256) void k_reduce_ln(
    const float* __restrict__ p0, const float* __restrict__ p1,
    const float* __restrict__ bo, const float* __restrict__ x,
    const float* __restrict__ g, const float* __restrict__ b,
    float* __restrict__ x2, bf16_t* __restrict__ m2) {
    const int row = blockIdx.x;
    const int t = threadIdx.x;
    const size_t off = (size_t)row * 1024;
    const float4 a0 = reinterpret_cast<const float4*>(p0 + off)[t];
    const float4 a1 = reinterpret_cast<const float4*>(p1 + off)[t];
    const float4 bb = reinterpret_cast<const float4*>(bo)[t];
    const float4 xv = reinterpret_cast<const float4*>(x + off)[t];
    float4 v;
    v.x = a0.x + a1.x + bb.x + xv.x;
    v.y = a0.y + a1.y + bb.y + xv.y;
    v.z = a0.z + a1.z + bb.z + xv.z;
    v.w = a0.w + a1.w + bb.w + xv.w;
    reinterpret_cast<float4*>(x2 + off)[t] = v;
    float s = v.x + v.y + v.z + v.w;
    float s2 = v.x * v.x + v.y * v.y + v.z * v.z + v.w * v.w;
#pragma unroll
    for (int mk = 32; mk >= 1; mk >>= 1) {
        s += __shfl_xor(s, mk);
        s2 += __shfl_xor(s2, mk);
    }
    __shared__ float red[8];
    const int w = t >> 6, l = t & 63;
    if (l == 0) { red[w] = s; red[4 + w] = s2; }
    __syncthreads();
    s = red[0] + red[1] + red[2] + red[3];
    s2 = red[4] + red[5] + red[6] + red[7];
    const float mu = s * (1.0f / 1024.0f);
    const float var = s2 * (1.0f / 1024.0f) - mu * mu;
    const float rs = rsqrtf(var + 1e-5f);
    const float4 gv = reinterpret_cast<const float4*>(g)[t];
    const float4 bv = reinterpret_cast<const float4*>(b)[t];
    bf16x4 o4;
    o4[0] = (bf16_t)((v.x - mu) * rs * gv.x + bv.x);
    o4[1] = (bf16_t)((v.y - mu) * rs * gv.y + bv.y);
    o4[2] = (bf16_t)((v.z - mu) * rs * gv.z + bv.z);
    o4[3] = (bf16_t)((v.w - mu) * rs * gv.w + bv.w);
    *reinterpret_cast<bf16x4*>(m2 + off + t * 4) = o4;
}

// ---------------- final reduce: d_out = pA + pB + b2 + x2
__global__ __launch_bounds__(256) void k_reduce_out(
    const float* __restrict__ pA, const float* __restrict__ pB,
    const float* __restrict__ b2, const float* __restrict__ x2,
    float* __restrict__ outp) {
    const size_t i = (size_t)blockIdx.x * 256 + threadIdx.x;  // float4 index
    const float4 a = reinterpret_cast<const float4*>(pA)[i];
    const float4 b = reinterpret_cast<const float4*>(pB)[i];
    const float4 c = reinterpret_cast<const float4*>(x2)[i];
    const float4 bi = reinterpret_cast<const float4*>(b2)[i & 255];
    float4 v;
    v.x = a.x + b.x + c.x + bi.x;
    v.y = a.y + b.y + c.y + bi.y;
    v.z = a.z + b.z + c.z + bi.z;
    v.w = a.w + b.w + c.w + bi.w;
    reinterpret_cast<float4*>(outp)[i] = v;
}

// ---------------- 8-wave phase-pipelined GEMM (m201 schedule)
// BM=256, BK=64, BN in {256,128}. 8 waves (2M x 4N).
// RACE-FIX (R5): LOADA band is H*128 + wr*64 so that phase 0 reads EXACTLY
// staging-half 0 and phase 2 exactly half 1; stage(half0)@p1, stage(half1)@p3
// are then ordered by each phase's per-wave lgkmcnt(0) + closing s_barrier.
// Counted vmcnt(LT), never 0 mid-loop. gridDim.z = split-K index (EPI_PART).
enum { EPI_QKV = 0, EPI_GELU = 1, EPI_PART = 2 };

template <int EPI, int BN>
__global__ __launch_bounds__(512, 2) void k_gemm8(
    const bf16_t* __restrict__ A, const bf16_t* __restrict__ BT,
    const float* __restrict__ bias0, const float* __restrict__ bias1,
    const float* __restrict__ bias2,
    float* __restrict__ outF, bf16_t* __restrict__ outB,
    bf16_t* __restrict__ outB2, bf16_t* __restrict__ outB3,
    int M, int N, int Ksub, int Kstr, long long zstride) {
    constexpr int BM = 256;
    constexpr int FJ = BN / 64;       // frag-cols per wave
    constexpr int FJH = FJ / 2;       // frag-cols per col-half
    constexpr int LA = 2;             // gload issues per A half-tile (128 rows)
    constexpr int LB = BN / 128;      // gload issues per B half-tile
    constexpr int LT = 2 * LA + 2 * LB;

    const int gx = gridDim.x;
    const int nwg = gx * gridDim.y;
    int lin = blockIdx.y * gx + blockIdx.x;
    if ((nwg & 7) == 0) lin = (lin & 7) * (nwg >> 3) + (lin >> 3);
    const int mbase = (lin / gx) * BM;
    const int nbase = (lin % gx) * BN;

    const bf16_t* Ab = A + (size_t)blockIdx.z * Ksub;
    const bf16_t* Bb = BT + (size_t)blockIdx.z * Ksub;
    float* poutF = outF;
    if constexpr (EPI == EPI_PART) poutF = outF + (size_t)blockIdx.z * zstride;

    const int t = threadIdx.x;
    const int w = t >> 6, l = t & 63;
    const int wr = w >> 2, wc = w & 3;
    const int lrow = l & 15, lg = l >> 4;

    __shared__ alignas(16) bf16_t As[2][BM * 64];
    __shared__ alignas(16) bf16_t Bs[2][BN * 64];

    f32x4 acc[8][FJ] = {};

    const int sr8 = t >> 3;                      // staging row 0..63
    const int ssw8 = ((t & 7) ^ (sr8 & 7)) * 8;  // pre-swizzled src chunk

    auto stageA = [&](int kt, int buf, int half) {
#pragma unroll
        for (int i = 0; i < LA; i++)
            async_lds16(Ab + (size_t)(mbase + half * 128 + i * 64 + sr8) * Kstr + (kt << 6) + ssw8,
                        &As[buf][(half * LA + i) * 4096 + t * 8]);
    };
    auto stageB = [&](int kt, int buf, int half) {
#pragma unroll
        for (int i = 0; i < LB; i++)
            async_lds16(Bb + (size_t)(nbase + half * (BN / 2) + i * 64 + sr8) * Kstr + (kt << 6) + ssw8,
                        &Bs[buf][(half * LB + i) * 4096 + t * 8]);
    };

// A reads: phase H reads LDS rows [H*128, H*128+128) == staging half H.
#define LOADA(DST, H)                                                        \
    _Pragma("unroll") for (int fi = 0; fi < 4; fi++) {                       \
        const int r_ = (H) * 128 + wr * 64 + fi * 16 + lrow;                 \
        _Pragma("unroll") for (int ks = 0; ks < 2; ks++)                     \
            DST[fi][ks] = *reinterpret_cast<const bf16x8*>(                  \
                &As[cur][r_ * 64 + (((ks * 4 + lg) ^ (r_ & 7)) * 8)]);       \
    }
#define LOADB(DST, V)                                                        \
    _Pragma("unroll") for (int fj = 0; fj < FJH; fj++) {                     \
        const int rb_ = wc * (BN / 4) + (V) * (BN / 8) + fj * 16 + lrow;     \
        _Pragma("unroll") for (int ks = 0; ks < 2; ks++)                     \
            DST[fj][ks] = *reinterpret_cast<const bf16x8*>(                  \
                &Bs[cur][rb_ * 64 + (((ks * 4 + lg) ^ (rb_ & 7)) * 8)]);     \
    }
#define MFMAQ(H, V, AF, BF)                                                  \
    __builtin_amdgcn_s_setprio(1);                                           \
    _Pragma("unroll") for (int fi = 0; fi < 4; fi++)                         \
    _Pragma("unroll") for (int fj = 0; fj < FJH; fj++)                       \
    _Pragma("unroll") for (int ks = 0; ks < 2; ks++)                         \
        acc[(H) * 4 + fi][(V) * FJH + fj] =                                  \
            __builtin_amdgcn_mfma_f32_16x16x32_bf16(                         \
                AF[fi][ks], BF[fj][ks],                                      \
                acc[(H) * 4 + fi][(V) * FJH + fj], 0, 0, 0);                 \
    __builtin_amdgcn_s_setprio(0);

    // prologue: tiles 0 and 1
    stageA(0, 0, 0); stageA(0, 0, 1); stageB(0, 0, 0); stageB(0, 0, 1);
    stageA(1, 1, 0); stageA(1, 1, 1); stageB(1, 1, 0); stageB(1, 1, 1);
    asm volatile("s_waitcnt vmcnt(%0)" ::"i"(LT) : "memory");
    __builtin_amdgcn_sched_barrier(0);
    __builtin_amdgcn_s_barrier();

    const int nt = Ksub >> 6;
    bf16x8 afrA[4][2], afrB[4][2], b0[FJH][2], b1[FJH][2];
    for (int kt = 0; kt < nt; kt++) {
        const int cur = kt & 1;
        const bool ds = (kt + 2) < nt;
        // ---- phase 0: read A-half0 + B-v0; MFMA quadrant (0,0)
        LOADA(afrA, 0)
        LOADB(b0, 0)
        if constexpr (BN == 256) asm volatile("s_waitcnt lgkmcnt(8)" ::: "memory");
        __builtin_amdgcn_s_barrier();
        asm volatile("s_waitcnt lgkmcnt(0)" ::: "memory");
        __builtin_amdgcn_sched_barrier(0);
        MFMAQ(0, 0, afrA, b0)
        __builtin_amdgcn_s_barrier();
        // ---- phase 1: read B-v1; stage A-half0 of kt+2 (half0 fully read @p0)
        LOADB(b1, 1)
        if (ds) stageA(kt + 2, cur, 0);
        __builtin_amdgcn_s_barrier();
        asm volatile("s_waitcnt lgkmcnt(0)" ::: "memory");
        __builtin_amdgcn_sched_barrier(0);
        MFMAQ(0, 1, afrA, b1)
        __builtin_amdgcn_s_barrier();
        // ---- phase 2: read A-half1; stage B-half0 (all B reads done @p0+p1)
        LOADA(afrB, 1)
        if (ds) stageB(kt + 2, cur, 0);
        __builtin_amdgcn_s_barrier();
        asm volatile("s_waitcnt lgkmcnt(0)" ::: "memory");
        __builtin_amdgcn_sched_barrier(0);
        MFMAQ(1, 1, afrB, b1)
        __builtin_amdgcn_s_barrier();
        // ---- phase 3: stage B-half1 + A-half1 (half1 reads retired @p2)
        if (ds) { stageB(kt + 2, cur, 1); stageA(kt + 2, cur, 1); }
        MFMAQ(1, 0, afrB, b0)
        if (ds) {
            asm volatile("s_waitcnt vmcnt(%0)" ::"i"(LT) : "memory");
        } else {
            asm volatile("s_waitcnt vmcnt(0)" ::: "memory");
        }
        __builtin_amdgcn_sched_barrier(0);
        __builtin_amdgcn_s_barrier();
    }

#pragma unroll
    for (int i = 0; i < 8; i++) {
#pragma unroll
        for (int j = 0; j < FJ; j++) {
            const int col = nbase + wc * (BN / 4) + j * 16 + lrow;
            float bj = 0.f;
            int kind = 0, cc = col;
            if constexpr (EPI == EPI_QKV) {
                kind = col >> 10; cc = col & 1023;
                bj = (kind == 0 ? bias0 : kind == 1 ? bias1 : bias2)[cc];
            } else if constexpr (EPI == EPI_GELU) {
                bj = bias0[col];
            }
#pragma unroll
            for (int r = 0; r < 4; r++) {
                // i = H*4+fi -> row = mbase + H*128 + wr*64 + fi*16 + lg*4 + r
                const int row = mbase + (i >> 2) * 128 + wr * 64 + (i & 3) * 16 + lg * 4 + r;
                const float v = acc[i][j][r] + bj;
                if constexpr (EPI == EPI_QKV) {
                    const int bidx = row >> 10, ns = row & 1023;
                    const int hh = cc >> 6, ch = cc & 63;
                    const int bhh = bidx * 16 + hh;
                    if (kind == 0)
                        outB[((size_t)bhh * 1024 + ns) * 64 + ch] = (bf16_t)(v * 0.125f);
                    else if (kind == 1)
                        outB2[((size_t)bhh * 1024 + ns) * 64 + ch] = (bf16_t)v;
                    else  // V stored transposed: [bh][ch][n]
                        outB3[((size_t)bhh * 64 + ch) * 1024 + ns] = (bf16_t)v;
                } else if constexpr (EPI == EPI_GELU) {
                    const float ge = 0.5f * v * (1.0f + erff(v * 0.70710678118654752f));
                    outB[(size_t)row * N + col] = (bf16_t)ge;
                } else {  // EPI_PART: raw f32 partial
                    poutF[(size_t)row * N + col] = v;
                }
            }
        }
    }
#undef LOADA
#undef LOADB
#undef MFMAQ
}

// ---------------- flash attention, causal, 1 block per (bh, 64-row q tile)
__global__ __launch_bounds__(256, 2) void k_attn(
    const bf16_t* __restrict__ q, const bf16_t* __restrict__ kk,
    const bf16_t* __restrict__ vt, const unsigned char* __restrict__ pad,
    bf16_t* __restrict__ o) {
    const int qt = blockIdx.x;   // 0..15
    const int bh = blockIdx.y;   // 0..63
    const int bb = bh >> 4, hh = bh & 15;
    const int t = threadIdx.x;
    const int w = t >> 6, l = t & 63;
    const int lrow = l & 15, lg = l >> 4;
    const int qbase = qt * 64;

    __shared__ alignas(16) bf16_t Ks[64 * 64];
    __shared__ alignas(16) bf16_t Vs[64 * 64];
    __shared__ alignas(16) bf16_t Ps[4][16 * 64];

    const size_t bh_off = (size_t)bh * 1024 * 64;
    const int qrow = qbase + w * 16 + lrow;
    bf16x8 qf[2];
#pragma unroll
    for (int ks = 0; ks < 2; ks++)
        qf[ks] = *reinterpret_cast<const bf16x8*>(q + bh_off + (size_t)qrow * 64 + ks * 32 + lg * 8);

    f32x4 oacc[4] = {};
    float mrow[4] = {-1e30f, -1e30f, -1e30f, -1e30f};
    float lsum[4] = {0.f, 0.f, 0.f, 0.f};

    const int sr = t >> 3;                // staging row 0..31
    const int ssw = ((t & 7) ^ (sr & 7)) * 8;  // swizzled source chunk offset

    for (int kb = 0; kb < qbase + 64; kb += 64) {
        __syncthreads();
        const bf16_t* kp = kk + bh_off + (size_t)kb * 64;
        async_lds16(kp + (size_t)sr * 64 + ssw, Ks + t * 8);
        async_lds16(kp + (size_t)(32 + sr) * 64 + ssw, Ks + 2048 + t * 8);
        const bf16_t* vp = vt + bh_off + kb;  // rows = channel, stride 1024
        async_lds16(vp + (size_t)sr * 1024 + ssw, Vs + t * 8);
        async_lds16(vp + (size_t)(32 + sr) * 1024 + ssw, Vs + 2048 + t * 8);
        __syncthreads();

        // S = Q K^T (16 q rows x 64 kv per wave)
        f32x4 s[4] = {};
#pragma unroll
        for (int ks = 0; ks < 2; ks++) {
#pragma unroll
            for (int jt = 0; jt < 4; jt++) {
                const int kr = jt * 16 + lrow;
                bf16x8 bfr = *reinterpret_cast<const bf16x8*>(
                    Ks + kr * 64 + (((ks * 4 + lg) ^ (kr & 7)) * 8));
                s[jt] = __builtin_amdgcn_mfma_f32_16x16x32_bf16(qf[ks], bfr, s[jt], 0, 0, 0);
            }
        }
        // causal + pad mask
#pragma unroll
        for (int jt = 0; jt < 4; jt++) {
            const int kvg = kb + jt * 16 + lrow;
            const bool padm = pad[bb * 1024 + kvg] != 0;
#pragma unroll
            for (int r = 0; r < 4; r++) {
                const int qg = qbase + w * 16 + lg * 4 + r;
                if (kvg > qg || padm) s[jt][r] = -1e30f;
            }
        }
        // online softmax (row groups of 16 lanes)
        float alpha[4];
#pragma unroll
        for (int r = 0; r < 4; r++) {
            float mx = fmaxf(fmaxf(s[0][r], s[1][r]), fmaxf(s[2][r], s[3][r]));
#pragma unroll
            for (int mk = 8; mk >= 1; mk >>= 1) mx = fmaxf(mx, __shfl_xor(mx, mk));
            const float mn = fmaxf(mrow[r], mx);
            alpha[r] = __expf(mrow[r] - mn);
            mrow[r] = mn;
        }
#pragma unroll
        for (int jt = 0; jt < 4; jt++)
#pragma unroll
            for (int r = 0; r < 4; r++)
                s[jt][r] = __expf(s[jt][r] - mrow[r]);
#pragma unroll
        for (int r = 0; r < 4; r++) {
            float sm = s[0][r] + s[1][r] + s[2][r] + s[3][r];
#pragma unroll
            for (int mk = 8; mk >= 1; mk >>= 1) sm += __shfl_xor(sm, mk);
            lsum[r] = lsum[r] * alpha[r] + sm;
        }
#pragma unroll
        for (int ct = 0; ct < 4; ct++)
#pragma unroll
            for (int r = 0; r < 4; r++)
                oacc[ct][r] *= alpha[r];
        // P -> LDS (per wave), swizzled, convert to A-fragment layout
#pragma unroll
        for (int jt = 0; jt < 4; jt++)
#pragma unroll
            for (int r = 0; r < 4; r++) {
                const int prow = lg * 4 + r;
                const int kvc = jt * 16 + lrow;
                Ps[w][prow * 64 + (((kvc >> 3) ^ (prow & 7)) * 8) + (kvc & 7)] = (bf16_t)s[jt][r];
            }
        // PV (same-wave LDS RAW; compiler orders DS ops within a wave)
#pragma unroll
        for (int ks = 0; ks < 2; ks++) {
            bf16x8 pa = *reinterpret_cast<const bf16x8*>(
                &Ps[w][lrow * 64 + (((ks * 4 + lg) ^ (lrow & 7)) * 8)]);
#pragma unroll
            for (int ct = 0; ct < 4; ct++) {
                const int vr = ct * 16 + lrow;
                bf16x8 vb = *reinterpret_cast<const bf16x8*>(
                    Vs + vr * 64 + (((ks * 4 + lg) ^ (vr & 7)) * 8));
                oacc[ct] = __builtin_amdgcn_mfma_f32_16x16x32_bf16(pa, vb, oacc[ct], 0, 0, 0);
            }
        }
    }
    // epilogue: o[b][n][h*64+ch] bf16
#pragma unroll
    for (int ct = 0; ct < 4; ct++) {
#pragma unroll
        for (int r = 0; r < 4; r++) {
            const int qg = qbase + w * 16 + lg * 4 + r;
            const float val = oacc[ct][r] / lsum[r];
            o[((size_t)bb * 1024 + qg) * 1024 + hh * 64 + ct * 16 + lrow] = (bf16_t)val;
        }
    }
}

extern "C" void kernel_launch(void* const* d_in, const int* in_sizes, int n_in,
                              void* d_out, int out_size, void* d_ws, size_t ws_size,
                              hipStream_t stream) {
    const float* x    = (const float*)d_in[0];
    const float* ln1g = (const float*)d_in[1];
    const float* ln1b = (const float*)d_in[2];
    const float* Wq   = (const float*)d_in[3];
    const float* bq   = (const float*)d_in[4];
    const float* Wk   = (const float*)d_in[5];
    const float* bk   = (const float*)d_in[6];
    const float* Wv   = (const float*)d_in[7];
    const float* bv   = (const float*)d_in[8];
    const float* Wo   = (const float*)d_in[9];
    const float* bo   = (const float*)d_in[10];
    const float* ln2g = (const float*)d_in[11];
    const float* ln2b = (const float*)d_in[12];
    const float* W1   = (const float*)d_in[13];
    const float* b1   = (const float*)d_in[14];
    const float* W2   = (const float*)d_in[15];
    const float* b2   = (const float*)d_in[16];
    const unsigned char* pad = (const unsigned char*)d_in[17];

    char* ws = (char*)d_ws;
    const size_t MB = 1024 * 1024;
    // layout (96MB total, heavy overlaying):
    bf16_t* WqkvT = (bf16_t*)(ws + 0 * MB);   // 6MB   [dead after QKV]
    bf16_t* WoT = (bf16_t*)(ws + 6 * MB);     // 2MB   [dead after O-proj]
    bf16_t* W1T = (bf16_t*)(ws + 8 * MB);     // 8MB   [dead after GELU]
    bf16_t* W2T = (bf16_t*)(ws + 16 * MB);    // 8MB   [dead after W2]
    bf16_t* h   = (bf16_t*)(ws + 24 * MB);    // 8MB   [dead after QKV]
    bf16_t* qb  = (bf16_t*)(ws + 32 * MB);    // 8MB   [dead after attn]
    bf16_t* kb  = (bf16_t*)(ws + 40 * MB);    // 8MB   [dead after attn]
    bf16_t* vb  = (bf16_t*)(ws + 48 * MB);    // 8MB   [dead after attn]
    bf16_t* ob  = (bf16_t*)(ws + 56 * MB);    // 8MB   [dead after O-proj]
    float*  ppO = (float*)(ws + 24 * MB);     // 2x16MB @24,40 [O-proj partials]
    float*  x2  = (float*)(ws + 56 * MB);     // 16MB  @56-72 [alive to end]
    bf16_t* m2  = (bf16_t*)(ws + 72 * MB);    // 8MB   @72-80 [dead after GELU]
    bf16_t* hid = (bf16_t*)(ws + 24 * MB);    // 32MB  @24-56 [dead after W2]
    float*  ppW0 = (float*)(ws + 0 * MB);     // 16MB  @0-16  [W2 partial z=0]
    float*  ppW1 = (float*)(ws + 80 * MB);    // 16MB  @80-96 [W2 partial z=1]

    const dim3 blk(256);
    const dim3 blk8(512);
    // weight transposes (f32 -> bf16, W^T); q/k/v packed into one 3072-row BT
    k_transpose_bf16<<<dim3(32, 32), blk, 0, stream>>>(Wq, WqkvT, 1024, 1024);
    k_transpose_bf16<<<dim3(32, 32), blk, 0, stream>>>(Wk, WqkvT + 1024 * 1024, 1024, 1024);
    k_transpose_bf16<<<dim3(32, 32), blk, 0, stream>>>(Wv, WqkvT + 2048 * 1024, 1024, 1024);
    k_transpose_bf16<<<dim3(32, 32), blk, 0, stream>>>(Wo, WoT, 1024, 1024);
    k_transpose_bf16<<<dim3(128, 32), blk, 0, stream>>>(W1, W1T, 1024, 4096);
    k_transpose_bf16<<<dim3(32, 128), blk, 0, stream>>>(W2, W2T, 4096, 1024);
    // LN1
    k_layernorm<<<4096, blk, 0, stream>>>(x, ln1g, ln1b, h);
    // fused QKV projection: M=4096, N=3072 -> 192 blocks
    k_gemm8<EPI_QKV, 256><<<dim3(12, 16), blk8, 0, stream>>>(
        h, WqkvT, bq, bk, bv, nullptr, qb, kb, vb, 4096, 3072, 1024, 1024, 0);
    // attention
    k_attn<<<dim3(16, 64), blk, 0, stream>>>(qb, kb, vb, pad, ob);
    // O-proj split-K x2 (one dispatch, 256 blocks): partials @24MB,@40MB
    k_gemm8<EPI_PART, 128><<<dim3(8, 16, 2), blk8, 0, stream>>>(
        ob, WoT, nullptr, nullptr, nullptr, ppO, nullptr, nullptr, nullptr,
        4096, 1024, 512, 1024, 4096ll * 1024);
    // reduce partials + bias + residual + LN2 -> x2 (f32) and m2 (bf16)
    k_reduce_ln<<<4096, blk, 0, stream>>>(ppO, ppO + 4096ll * 1024, bo, x,
                                          ln2g, ln2b, x2, m2);
    // MLP up + GELU: M=4096, N=4096 -> 256 blocks
    k_gemm8<EPI_GELU, 256><<<dim3(16, 16), blk8, 0, stream>>>(
        m2, W1T, b1, nullptr, nullptr, nullptr, hid, nullptr, nullptr,
        4096, 4096, 1024, 1024, 0);
    // MLP down split-K x2 (256 blocks): z=0 -> @0MB, z=1 -> @80MB
    k_gemm8<EPI_PART, 128><<<dim3(8, 16, 2), blk8, 0, stream>>>(
        hid, W2T, nullptr, nullptr, nullptr, ppW0, nullptr, nullptr, nullptr,
        4096, 1024, 2048, 4096, 20ll * 1024 * 1024);
    // final reduce: d_out = ppW0 + ppW1 + b2 + x2
    k_reduce_out<<<4096, blk, 0, stream>>>(ppW0, ppW1, b2, x2, (float*)d_out);
}

// Round 7
// 258.520 us; speedup vs baseline: 1.1605x; 1.1093x over previous
//
#include <hip/hip_runtime.h>
#include <hip/hip_bf16.h>
#include <cmath>

typedef __bf16 bf16_t;
typedef __bf16 bf16x8 __attribute__((ext_vector_type(8)));
typedef __bf16 bf16x4 __attribute__((ext_vector_type(4)));
typedef float f32x4 __attribute__((ext_vector_type(4)));

#define AS1 __attribute__((address_space(1)))
#define AS3 __attribute__((address_space(3)))

__device__ __forceinline__ void async_lds16(const void* g, void* s) {
    __builtin_amdgcn_global_load_lds((const AS1 void*)g, (AS3 void*)s, 16, 0, 0);
}

// ---------------- weight transpose + cast: src (R x C) f32 -> dst (C x R) bf16
__global__ __launch_bounds__(256) void k_transpose_bf16(
    const float* __restrict__ src, bf16_t* __restrict__ dst, int R, int C) {
    __shared__ float tile[32][33];
    const int tx = threadIdx.x & 31, ty = threadIdx.x >> 5;
    const int r0 = blockIdx.y << 5, c0 = blockIdx.x << 5;
#pragma unroll
    for (int i = 0; i < 32; i += 8)
        tile[ty + i][tx] = src[(size_t)(r0 + ty + i) * C + c0 + tx];
    __syncthreads();
#pragma unroll
    for (int i = 0; i < 32; i += 8)
        dst[(size_t)(c0 + ty + i) * R + r0 + tx] = (bf16_t)tile[tx][ty + i];
}

// ---------------- layernorm: x (rows x 1024) f32 -> out bf16
__global__ __launch_bounds__(256) void k_layernorm(
    const float* __restrict__ x, const float* __restrict__ g,
    const float* __restrict__ b, bf16_t* __restrict__ out) {
    const int row = blockIdx.x;
    const int t = threadIdx.x;
    const float4 xv = reinterpret_cast<const float4*>(x + (size_t)row * 1024)[t];
    float s = xv.x + xv.y + xv.z + xv.w;
    float s2 = xv.x * xv.x + xv.y * xv.y + xv.z * xv.z + xv.w * xv.w;
#pragma unroll
    for (int mk = 32; mk >= 1; mk >>= 1) {
        s += __shfl_xor(s, mk);
        s2 += __shfl_xor(s2, mk);
    }
    __shared__ float red[8];
    const int w = t >> 6, l = t & 63;
    if (l == 0) { red[w] = s; red[4 + w] = s2; }
    __syncthreads();
    s = red[0] + red[1] + red[2] + red[3];
    s2 = red[4] + red[5] + red[6] + red[7];
    const float mu = s * (1.0f / 1024.0f);
    const float var = s2 * (1.0f / 1024.0f) - mu * mu;
    const float rs = rsqrtf(var + 1e-5f);
    const float4 gv = reinterpret_cast<const float4*>(g)[t];
    const float4 bv = reinterpret_cast<const float4*>(b)[t];
    bf16x4 o4;
    o4[0] = (bf16_t)((xv.x - mu) * rs * gv.x + bv.x);
    o4[1] = (bf16_t)((xv.y - mu) * rs * gv.y + bv.y);
    o4[2] = (bf16_t)((xv.z - mu) * rs * gv.z + bv.z);
    o4[3] = (bf16_t)((xv.w - mu) * rs * gv.w + bv.w);
    *reinterpret_cast<bf16x4*>(out + (size_t)row * 1024 + t * 4) = o4;
}

// ---------------- partial reduce + bias + residual + fused LN -> x2 (f32), m2 (bf16)
__global__ __launch_bounds__(256) void k_reduce_ln(
    const float* __restrict__ p0, const float* __restrict__ p1,
    const float* __restrict__ bo, const float* __restrict__ x,
    const float* __restrict__ g, const float* __restrict__ b,
    float* __restrict__ x2, bf16_t* __restrict__ m2) {
    const int row = blockIdx.x;
    const int t = threadIdx.x;
    const size_t off = (size_t)row * 1024;
    const float4 a0 = reinterpret_cast<const float4*>(p0 + off)[t];
    const float4 a1 = reinterpret_cast<const float4*>(p1 + off)[t];
    const float4 bb = reinterpret_cast<const float4*>(bo)[t];
    const float4 xv = reinterpret_cast<const float4*>(x + off)[t];
    float4 v;
    v.x = a0.x + a1.x + bb.x + xv.x;
    v.y = a0.y + a1.y + bb.y + xv.y;
    v.z = a0.z + a1.z + bb.z + xv.z;
    v.w = a0.w + a1.w + bb.w + xv.w;
    reinterpret_cast<float4*>(x2 + off)[t] = v;
    float s = v.x + v.y + v.z + v.w;
    float s2 = v.x * v.x + v.y * v.y + v.z * v.z + v.w * v.w;
#pragma unroll
    for (int mk = 32; mk >= 1; mk >>= 1) {
        s += __shfl_xor(s, mk);
        s2 += __shfl_xor(s2, mk);
    }
    __shared__ float red[8];
    const int w = t >> 6, l = t & 63;
    if (l == 0) { red[w] = s; red[4 + w] = s2; }
    __syncthreads();
    s = red[0] + red[1] + red[2] + red[3];
    s2 = red[4] + red[5] + red[6] + red[7];
    const float mu = s * (1.0f / 1024.0f);
    const float var = s2 * (1.0f / 1024.0f) - mu * mu;
    const float rs = rsqrtf(var + 1e-5f);
    const float4 gv = reinterpret_cast<const float4*>(g)[t];
    const float4 bv = reinterpret_cast<const float4*>(b)[t];
    bf16x4 o4;
    o4[0] = (bf16_t)((v.x - mu) * rs * gv.x + bv.x);
    o4[1] = (bf16_t)((v.y - mu) * rs * gv.y + bv.y);
    o4[2] = (bf16_t)((v.z - mu) * rs * gv.z + bv.z);
    o4[3] = (bf16_t)((v.w - mu) * rs * gv.w + bv.w);
    *reinterpret_cast<bf16x4*>(m2 + off + t * 4) = o4;
}

// ---------------- final reduce: d_out = pA + pB + b2 + x2
__global__ __launch_bounds__(256) void k_reduce_out(
    const float* __restrict__ pA, const float* __restrict__ pB,
    const float* __restrict__ b2, const float* __restrict__ x2,
    float* __restrict__ outp) {
    const size_t i = (size_t)blockIdx.x * 256 + threadIdx.x;  // float4 index
    const float4 a = reinterpret_cast<const float4*>(pA)[i];
    const float4 b = reinterpret_cast<const float4*>(pB)[i];
    const float4 c = reinterpret_cast<const float4*>(x2)[i];
    const float4 bi = reinterpret_cast<const float4*>(b2)[i & 255];
    float4 v;
    v.x = a.x + b.x + c.x + bi.x;
    v.y = a.y + b.y + c.y + bi.y;
    v.z = a.z + b.z + c.z + bi.z;
    v.w = a.w + b.w + c.w + bi.w;
    reinterpret_cast<float4*>(outp)[i] = v;
}

// ---------------- 128x128 GEMM, BK=32, 4 waves, 3-buffer LDS ring
// Prefetch distance 2 via global_load_lds; raw s_barrier + counted vmcnt(4)
// (never drains the in-flight prefetches). 48KB LDS -> ~3 blocks/CU for
// cross-block latency hiding (m97 regime). Swizzle chunk^((row>>1)&3) on
// both staging source and ds_read (verified 0 bank conflicts in R2/R3).
enum { EPI_QKV = 0, EPI_GELU = 1, EPI_PART = 2 };

template <int EPI>
__global__ __launch_bounds__(256, 3) void k_gemm2(
    const bf16_t* __restrict__ A, const bf16_t* __restrict__ BT,
    const float* __restrict__ bias0, const float* __restrict__ bias1,
    const float* __restrict__ bias2,
    float* __restrict__ outF, bf16_t* __restrict__ outB,
    bf16_t* __restrict__ outB2, bf16_t* __restrict__ outB3,
    int M, int N, int Ksub, int Kstr, long long zstride) {
    const int gx = gridDim.x;
    const int nwg = gx * gridDim.y;
    int lin = blockIdx.y * gx + blockIdx.x;
    if ((nwg & 7) == 0) lin = (lin & 7) * (nwg >> 3) + (lin >> 3);
    const int mbase = (lin / gx) * 128;
    const int nbase = (lin % gx) * 128;

    const bf16_t* Ab = A + (size_t)blockIdx.z * Ksub;
    const bf16_t* Bb = BT + (size_t)blockIdx.z * Ksub;
    float* poutF = outF;
    if constexpr (EPI == EPI_PART) poutF = outF + (size_t)blockIdx.z * zstride;

    const int t = threadIdx.x;
    const int w = t >> 6, l = t & 63;
    const int wr = w >> 1, wc = w & 1;
    const int lrow = l & 15, lg = l >> 4;

    __shared__ alignas(16) bf16_t As[3][128 * 32];
    __shared__ alignas(16) bf16_t Bs[3][128 * 32];

    f32x4 acc[4][4] = {};

    const int sr = t >> 2;                        // staging row 0..63
    const int sc = t & 3;                         // 16B chunk 0..3
    const int ssw = (sc ^ ((sr >> 1) & 3)) * 8;   // pre-swizzled src offset

    auto stage = [&](int ks, int buf) {
        const int k0 = ks << 5;
#pragma unroll
        for (int c = 0; c < 2; c++)
            async_lds16(Ab + (size_t)(mbase + c * 64 + sr) * Kstr + k0 + ssw,
                        &As[buf][c * 2048 + t * 8]);
#pragma unroll
        for (int c = 0; c < 2; c++)
            async_lds16(Bb + (size_t)(nbase + c * 64 + sr) * Kstr + k0 + ssw,
                        &Bs[buf][c * 2048 + t * 8]);
    };

    stage(0, 0);
    stage(1, 1);
    const int nt = Ksub >> 5;
    int cur = 0;
    for (int tt = 0; tt < nt; tt++) {
        // gate: stage(tt) landed; stage(tt+1) (4 loads) may stay in flight
        asm volatile("s_waitcnt vmcnt(4)" ::: "memory");
        __builtin_amdgcn_sched_barrier(0);
        __builtin_amdgcn_s_barrier();   // all waves' reads of buf[(tt-1)%3] retired
        __builtin_amdgcn_sched_barrier(0);
        if (tt + 2 < nt) {
            int nb = cur + 2; if (nb >= 3) nb -= 3;
            stage(tt + 2, nb);          // overwrites buf of tt-1 (safe post-barrier)
        }
        bf16x8 a[4], b[4];
#pragma unroll
        for (int i = 0; i < 4; i++) {
            const int r = wr * 64 + i * 16 + lrow;
            a[i] = *reinterpret_cast<const bf16x8*>(
                &As[cur][r * 32 + ((lg ^ ((r >> 1) & 3)) * 8)]);
        }
#pragma unroll
        for (int j = 0; j < 4; j++) {
            const int r = wc * 64 + j * 16 + lrow;
            b[j] = *reinterpret_cast<const bf16x8*>(
                &Bs[cur][r * 32 + ((lg ^ ((r >> 1) & 3)) * 8)]);
        }
        __builtin_amdgcn_s_setprio(1);
#pragma unroll
        for (int i = 0; i < 4; i++)
#pragma unroll
            for (int j = 0; j < 4; j++)
                acc[i][j] = __builtin_amdgcn_mfma_f32_16x16x32_bf16(a[i], b[j], acc[i][j], 0, 0, 0);
        __builtin_amdgcn_s_setprio(0);
        cur = cur + 1; if (cur >= 3) cur = 0;
    }

#pragma unroll
    for (int i = 0; i < 4; i++) {
#pragma unroll
        for (int j = 0; j < 4; j++) {
            const int col = nbase + wc * 64 + j * 16 + lrow;
            float bj = 0.f;
            int kind = 0, cc = col;
            if constexpr (EPI == EPI_QKV) {
                kind = col >> 10; cc = col & 1023;
                bj = (kind == 0 ? bias0 : kind == 1 ? bias1 : bias2)[cc];
            } else if constexpr (EPI == EPI_GELU) {
                bj = bias0[col];
            }
#pragma unroll
            for (int r = 0; r < 4; r++) {
                const int row = mbase + wr * 64 + i * 16 + lg * 4 + r;
                const float v = acc[i][j][r] + bj;
                if constexpr (EPI == EPI_QKV) {
                    const int bidx = row >> 10, ns = row & 1023;
                    const int hh = cc >> 6, ch = cc & 63;
                    const int bhh = bidx * 16 + hh;
                    if (kind == 0)
                        outB[((size_t)bhh * 1024 + ns) * 64 + ch] = (bf16_t)(v * 0.125f);
                    else if (kind == 1)
                        outB2[((size_t)bhh * 1024 + ns) * 64 + ch] = (bf16_t)v;
                    else  // V stored transposed: [bh][ch][n]
                        outB3[((size_t)bhh * 64 + ch) * 1024 + ns] = (bf16_t)v;
                } else if constexpr (EPI == EPI_GELU) {
                    const float ge = 0.5f * v * (1.0f + erff(v * 0.70710678118654752f));
                    outB[(size_t)row * N + col] = (bf16_t)ge;
                } else {  // EPI_PART: raw f32 partial
                    poutF[(size_t)row * N + col] = v;
                }
            }
        }
    }
}

// ---------------- flash attention, causal; 1D grid, qt DESCENDING (LPT)
__global__ __launch_bounds__(256, 4) void k_attn(
    const bf16_t* __restrict__ q, const bf16_t* __restrict__ kk,
    const bf16_t* __restrict__ vt, const unsigned char* __restrict__ pad,
    bf16_t* __restrict__ o) {
    const int qt = 15 - (blockIdx.x >> 6);   // longest blocks dispatch first
    const int bh = blockIdx.x & 63;
    const int bb = bh >> 4, hh = bh & 15;
    const int t = threadIdx.x;
    const int w = t >> 6, l = t & 63;
    const int lrow = l & 15, lg = l >> 4;
    const int qbase = qt * 64;

    __shared__ alignas(16) bf16_t Ks[64 * 64];
    __shared__ alignas(16) bf16_t Vs[64 * 64];
    __shared__ alignas(16) bf16_t Ps[4][16 * 64];

    const size_t bh_off = (size_t)bh * 1024 * 64;
    const int qrow = qbase + w * 16 + lrow;
    bf16x8 qf[2];
#pragma unroll
    for (int ks = 0; ks < 2; ks++)
        qf[ks] = *reinterpret_cast<const bf16x8*>(q + bh_off + (size_t)qrow * 64 + ks * 32 + lg * 8);

    f32x4 oacc[4] = {};
    float mrow[4] = {-1e30f, -1e30f, -1e30f, -1e30f};
    float lsum[4] = {0.f, 0.f, 0.f, 0.f};

    const int sr = t >> 3;                // staging row 0..31
    const int ssw = ((t & 7) ^ (sr & 7)) * 8;  // swizzled source chunk offset

    for (int kb = 0; kb < qbase + 64; kb += 64) {
        __syncthreads();
        const bf16_t* kp = kk + bh_off + (size_t)kb * 64;
        async_lds16(kp + (size_t)sr * 64 + ssw, Ks + t * 8);
        async_lds16(kp + (size_t)(32 + sr) * 64 + ssw, Ks + 2048 + t * 8);
        const bf16_t* vp = vt + bh_off + kb;  // rows = channel, stride 1024
        async_lds16(vp + (size_t)sr * 1024 + ssw, Vs + t * 8);
        async_lds16(vp + (size_t)(32 + sr) * 1024 + ssw, Vs + 2048 + t * 8);
        __syncthreads();

        // S = Q K^T (16 q rows x 64 kv per wave)
        f32x4 s[4] = {};
#pragma unroll
        for (int ks = 0; ks < 2; ks++) {
#pragma unroll
            for (int jt = 0; jt < 4; jt++) {
                const int kr = jt * 16 + lrow;
                bf16x8 bfr = *reinterpret_cast<const bf16x8*>(
                    Ks + kr * 64 + (((ks * 4 + lg) ^ (kr & 7)) * 8));
                s[jt] = __builtin_amdgcn_mfma_f32_16x16x32_bf16(qf[ks], bfr, s[jt], 0, 0, 0);
            }
        }
        // causal + pad mask
#pragma unroll
        for (int jt = 0; jt < 4; jt++) {
            const int kvg = kb + jt * 16 + lrow;
            const bool padm = pad[bb * 1024 + kvg] != 0;
#pragma unroll
            for (int r = 0; r < 4; r++) {
                const int qg = qbase + w * 16 + lg * 4 + r;
                if (kvg > qg || padm) s[jt][r] = -1e30f;
            }
        }
        // online softmax (row groups of 16 lanes)
        float alpha[4];
#pragma unroll
        for (int r = 0; r < 4; r++) {
            float mx = fmaxf(fmaxf(s[0][r], s[1][r]), fmaxf(s[2][r], s[3][r]));
#pragma unroll
            for (int mk = 8; mk >= 1; mk >>= 1) mx = fmaxf(mx, __shfl_xor(mx, mk));
            const float mn = fmaxf(mrow[r], mx);
            alpha[r] = __expf(mrow[r] - mn);
            mrow[r] = mn;
        }
#pragma unroll
        for (int jt = 0; jt < 4; jt++)
#pragma unroll
            for (int r = 0; r < 4; r++)
                s[jt][r] = __expf(s[jt][r] - mrow[r]);
#pragma unroll
        for (int r = 0; r < 4; r++) {
            float sm = s[0][r] + s[1][r] + s[2][r] + s[3][r];
#pragma unroll
            for (int mk = 8; mk >= 1; mk >>= 1) sm += __shfl_xor(sm, mk);
            lsum[r] = lsum[r] * alpha[r] + sm;
        }
#pragma unroll
        for (int ct = 0; ct < 4; ct++)
#pragma unroll
            for (int r = 0; r < 4; r++)
                oacc[ct][r] *= alpha[r];
        // P -> LDS (per wave), swizzled, convert to A-fragment layout
#pragma unroll
        for (int jt = 0; jt < 4; jt++)
#pragma unroll
            for (int r = 0; r < 4; r++) {
                const int prow = lg * 4 + r;
                const int kvc = jt * 16 + lrow;
                Ps[w][prow * 64 + (((kvc >> 3) ^ (prow & 7)) * 8) + (kvc & 7)] = (bf16_t)s[jt][r];
            }
        // PV (same-wave LDS RAW; compiler orders DS ops within a wave)
#pragma unroll
        for (int ks = 0; ks < 2; ks++) {
            bf16x8 pa = *reinterpret_cast<const bf16x8*>(
                &Ps[w][lrow * 64 + (((ks * 4 + lg) ^ (lrow & 7)) * 8)]);
#pragma unroll
            for (int ct = 0; ct < 4; ct++) {
                const int vr = ct * 16 + lrow;
                bf16x8 vb = *reinterpret_cast<const bf16x8*>(
                    Vs + vr * 64 + (((ks * 4 + lg) ^ (vr & 7)) * 8));
                oacc[ct] = __builtin_amdgcn_mfma_f32_16x16x32_bf16(pa, vb, oacc[ct], 0, 0, 0);
            }
        }
    }
    // epilogue: o[b][n][h*64+ch] bf16
#pragma unroll
    for (int ct = 0; ct < 4; ct++) {
#pragma unroll
        for (int r = 0; r < 4; r++) {
            const int qg = qbase + w * 16 + lg * 4 + r;
            const float val = oacc[ct][r] / lsum[r];
            o[((size_t)bb * 1024 + qg) * 1024 + hh * 64 + ct * 16 + lrow] = (bf16_t)val;
        }
    }
}

extern "C" void kernel_launch(void* const* d_in, const int* in_sizes, int n_in,
                              void* d_out, int out_size, void* d_ws, size_t ws_size,
                              hipStream_t stream) {
    const float* x    = (const float*)d_in[0];
    const float* ln1g = (const float*)d_in[1];
    const float* ln1b = (const float*)d_in[2];
    const float* Wq   = (const float*)d_in[3];
    const float* bq   = (const float*)d_in[4];
    const float* Wk   = (const float*)d_in[5];
    const float* bk   = (const float*)d_in[6];
    const float* Wv   = (const float*)d_in[7];
    const float* bv   = (const float*)d_in[8];
    const float* Wo   = (const float*)d_in[9];
    const float* bo   = (const float*)d_in[10];
    const float* ln2g = (const float*)d_in[11];
    const float* ln2b = (const float*)d_in[12];
    const float* W1   = (const float*)d_in[13];
    const float* b1   = (const float*)d_in[14];
    const float* W2   = (const float*)d_in[15];
    const float* b2   = (const float*)d_in[16];
    const unsigned char* pad = (const unsigned char*)d_in[17];

    char* ws = (char*)d_ws;
    const size_t MB = 1024 * 1024;
    // layout (96MB total, heavy overlaying):
    bf16_t* WqkvT = (bf16_t*)(ws + 0 * MB);   // 6MB   [dead after QKV]
    bf16_t* WoT = (bf16_t*)(ws + 6 * MB);     // 2MB   [dead after O-proj]
    bf16_t* W1T = (bf16_t*)(ws + 8 * MB);     // 8MB   [dead after GELU]
    bf16_t* W2T = (bf16_t*)(ws + 16 * MB);    // 8MB   [dead after W2]
    bf16_t* h   = (bf16_t*)(ws + 24 * MB);    // 8MB   [dead after QKV]
    bf16_t* qb  = (bf16_t*)(ws + 32 * MB);    // 8MB   [dead after attn]
    bf16_t* kb  = (bf16_t*)(ws + 40 * MB);    // 8MB   [dead after attn]
    bf16_t* vb  = (bf16_t*)(ws + 48 * MB);    // 8MB   [dead after attn]
    bf16_t* ob  = (bf16_t*)(ws + 56 * MB);    // 8MB   [dead after O-proj]
    float*  ppO = (float*)(ws + 24 * MB);     // 2x16MB @24,40 [O-proj partials]
    float*  x2  = (float*)(ws + 56 * MB);     // 16MB  @56-72 [alive to end]
    bf16_t* m2  = (bf16_t*)(ws + 72 * MB);    // 8MB   @72-80 [dead after GELU]
    bf16_t* hid = (bf16_t*)(ws + 24 * MB);    // 32MB  @24-56 [dead after W2]
    float*  ppW0 = (float*)(ws + 0 * MB);     // 16MB  @0-16  [W2 partial z=0]
    float*  ppW1 = (float*)(ws + 80 * MB);    // 16MB  @80-96 [W2 partial z=1]

    const dim3 blk(256);
    // weight transposes (f32 -> bf16, W^T); q/k/v packed into one 3072-row BT
    k_transpose_bf16<<<dim3(32, 32), blk, 0, stream>>>(Wq, WqkvT, 1024, 1024);
    k_transpose_bf16<<<dim3(32, 32), blk, 0, stream>>>(Wk, WqkvT + 1024 * 1024, 1024, 1024);
    k_transpose_bf16<<<dim3(32, 32), blk, 0, stream>>>(Wv, WqkvT + 2048 * 1024, 1024, 1024);
    k_transpose_bf16<<<dim3(32, 32), blk, 0, stream>>>(Wo, WoT, 1024, 1024);
    k_transpose_bf16<<<dim3(128, 32), blk, 0, stream>>>(W1, W1T, 1024, 4096);
    k_transpose_bf16<<<dim3(32, 128), blk, 0, stream>>>(W2, W2T, 4096, 1024);
    // LN1
    k_layernorm<<<4096, blk, 0, stream>>>(x, ln1g, ln1b, h);
    // fused QKV projection: M=4096, N=3072 -> 24x32 = 768 blocks (~3/CU)
    k_gemm2<EPI_QKV><<<dim3(24, 32), blk, 0, stream>>>(
        h, WqkvT, bq, bk, bv, nullptr, qb, kb, vb, 4096, 3072, 1024, 1024, 0);
    // attention: 1D, qt descending (LPT)
    k_attn<<<1024, blk, 0, stream>>>(qb, kb, vb, pad, ob);
    // O-proj split-K x2: 8x32x2 = 512 blocks, K_sub=512
    k_gemm2<EPI_PART><<<dim3(8, 32, 2), blk, 0, stream>>>(
        ob, WoT, nullptr, nullptr, nullptr, ppO, nullptr, nullptr, nullptr,
        4096, 1024, 512, 1024, 4096ll * 1024);
    // reduce partials + bias + residual + LN2 -> x2 (f32) and m2 (bf16)
    k_reduce_ln<<<4096, blk, 0, stream>>>(ppO, ppO + 4096ll * 1024, bo, x,
                                          ln2g, ln2b, x2, m2);
    // MLP up + GELU: 32x32 = 1024 blocks
    k_gemm2<EPI_GELU><<<dim3(32, 32), blk, 0, stream>>>(
        m2, W1T, b1, nullptr, nullptr, nullptr, hid, nullptr, nullptr,
        4096, 4096, 1024, 1024, 0);
    // MLP down split-K x2: 8x32x2 = 512 blocks, K_sub=2048
    k_gemm2<EPI_PART><<<dim3(8, 32, 2), blk, 0, stream>>>(
        hid, W2T, nullptr, nullptr, nullptr, ppW0, nullptr, nullptr, nullptr,
        4096, 1024, 2048, 4096, 20ll * 1024 * 1024);
    // final reduce: d_out = ppW0 + ppW1 + b2 + x2
    k_reduce_out<<<4096, blk, 0, stream>>>(ppW0, ppW1, b2, x2, (float*)d_out);
}